// Round 10
// baseline (54.957 us; speedup 1.0000x reference)
//
#include <hip/hip_runtime.h>
#include <math.h>

#define NN 18
#define T_STEPS 1280
#define T1LEN 1278   // T-2 (after conv1)
#define T2LEN 1276   // T-4 (after conv2)
#define TC2 92
#define NCHUNK2 ((T2LEN + TC2 - 1) / TC2)  // 14
#define NBLK (NCHUNK2 * NN)                // 252  (<= 256 CUs -> 1 block/CU)
#define DOT_BLOCKS 512
#define NGRP 32                             // election groups of 16 blocks

typedef __attribute__((ext_vector_type(8))) short short8;
typedef __attribute__((ext_vector_type(4))) float f32x4;

__device__ __forceinline__ unsigned short f2bf(float v) {
    unsigned u = __builtin_bit_cast(unsigned, v);
    u = u + 0x7fff + ((u >> 16) & 1);          // RNE
    return (unsigned short)(u >> 16);
}
__device__ __forceinline__ float bf2f(unsigned short h) {
    unsigned u = ((unsigned)h) << 16;
    return __builtin_bit_cast(float, u);
}
// swizzled ushort index for [row][c] bf16 tiles read as uint4 A-fragments (verified R3-R8)
__device__ __forceinline__ int swz(int row, int c) {
    return row * 64 + (((c >> 3) ^ (row & 7)) << 3) + (c & 7);
}

// =========== K1: per (node, t-chunk 92): x -> conv1(GLU) -> cheb(MFMA) -> conv2(MFMA)
//   -> GLU -> T2 fp32 + BN partials. Weights converted in-register; 1 block/CU. ===========
__global__ __launch_bounds__(256) void k_fuse(const float* __restrict__ x,
        const float* __restrict__ w1a, const float* __restrict__ b1a,
        const float* __restrict__ w1b, const float* __restrict__ b1b,
        const float* __restrict__ w1c, const float* __restrict__ b1c,
        const float* __restrict__ cw, const float* __restrict__ cb,
        const float* __restrict__ w2a, const float* __restrict__ w2b,
        const float* __restrict__ w2c,
        const float* __restrict__ b2a, const float* __restrict__ b2b,
        const float* __restrict__ b2c,
        float* __restrict__ T2, float* __restrict__ parts, int* __restrict__ cnts) {
    __shared__ float xs[104];
    __shared__ uint4 t1H[768], t1L[768];   // 96 rows x 64 bf16 (swizzled)
    __shared__ uint4 t2H[784], t2L[784];   // 98 rows (96,97 zero)
    __shared__ float red1[256], red2[256];
    int b = blockIdx.x;
    int node = b / NCHUNK2, chunk = b % NCHUNK2;
    int t0 = chunk * TC2;
    int tid = threadIdx.x;
    int l = tid & 63, w = tid >> 6;
    if (b == 0 && tid < NGRP + 1) cnts[tid * 32] = 0;   // zero election counters for K2

    // ---- stage + normalize 98 x values for this node ----
    if (tid < 98) {
        int xt = t0 + tid;
        float v = (xt < T_STEPS) ? x[xt * NN + node] : 0.f;
        xs[tid] = v / fmaxf(fabsf(v), 1e-12f);
    }
    __syncthreads();

    // ---- conv1 + GLU + relu -> t1 tile rows 0..95 (bf16 hi/lo, swizzled) ----
    {
        unsigned short* tH = (unsigned short*)t1H;
        unsigned short* tL = (unsigned short*)t1L;
        int c = l;
        float wa0 = w1a[c*3], wa1 = w1a[c*3+1], wa2 = w1a[c*3+2];
        float wb0 = w1b[c*3], wb1 = w1b[c*3+1], wb2 = w1b[c*3+2];
        float wc0 = w1c[c*3], wc1 = w1c[c*3+1], wc2 = w1c[c*3+2];
        float ba = b1a[c], bb = b1b[c], bc = b1c[c];
        #pragma unroll
        for (int j = 0; j < 24; ++j) {
            int r = w * 24 + j;            // local T1 row, time t0 + r
            float x0 = xs[r], x1 = xs[r + 1], x2 = xs[r + 2];
            float pa = fmaf(wa2, x2, fmaf(wa1, x1, fmaf(wa0, x0, ba)));
            float pb = fmaf(wb2, x2, fmaf(wb1, x1, fmaf(wb0, x0, bb)));
            float pc_ = fmaf(wc2, x2, fmaf(wc1, x1, fmaf(wc0, x0, bc)));
            float q = 1.0f / (1.0f + expf(-pb));
            float v = fmaxf(pa * q + pc_, 0.f);
            if (t0 + r >= T1LEN) v = 0.f;
            unsigned short hi = f2bf(v);
            int sw = swz(r, c);
            tH[sw] = hi;
            tL[sw] = f2bf(v - bf2f(hi));
        }
    }

    // ---- conv2 B fragments: load + split in-register from global fp32 (L2-hot) ----
    short8 bh[3][6], bl[3][6];
    {
        int co_b = w * 16 + (l & 15);
        #pragma unroll
        for (int ct = 0; ct < 3; ++ct) {
            const float* wsrc = (ct == 0) ? w2a : (ct == 1 ? w2b : w2c);
            #pragma unroll
            for (int kb = 0; kb < 6; ++kb) {
                int k = kb >> 1;
                #pragma unroll
                for (int j = 0; j < 8; ++j) {
                    int ci = (kb & 1) * 32 + (l >> 4) * 8 + j;
                    float v = wsrc[co_b * 192 + ci * 3 + k];
                    unsigned short hi = f2bf(v);
                    bh[ct][kb][j] = (short)hi;
                    bl[ct][kb][j] = (short)f2bf(v - bf2f(hi));
                }
            }
        }
    }
    // ---- cheb B fragments from cw (verified) ----
    int d = w * 16 + (l & 15);
    short8 cbh[2], cbl[2];
    #pragma unroll
    for (int kb = 0; kb < 2; ++kb) {
        #pragma unroll
        for (int j = 0; j < 8; ++j) {
            float v = cw[(kb * 32 + (l >> 4) * 8 + j) * 64 + d];
            unsigned short hi = f2bf(v);
            cbh[kb][j] = (short)hi;
            cbl[kb][j] = (short)f2bf(v - bf2f(hi));
        }
    }
    __syncthreads();

    // ---- cheb MFMA (6 M-tiles) -> t2 tile rows 0..95; zero 96..97 ----
    {
        f32x4 acc1[6];
        #pragma unroll
        for (int mt = 0; mt < 6; ++mt) acc1[mt] = (f32x4){0.f,0.f,0.f,0.f};
        #pragma unroll
        for (int kb = 0; kb < 2; ++kb) {
            #pragma unroll
            for (int mt = 0; mt < 6; ++mt) {
                int row = mt * 16 + (l & 15);
                int cbi = kb * 4 + (l >> 4);
                int si = row * 8 + (cbi ^ (row & 7));
                short8 ah = __builtin_bit_cast(short8, t1H[si]);
                short8 al = __builtin_bit_cast(short8, t1L[si]);
                acc1[mt] = __builtin_amdgcn_mfma_f32_16x16x32_bf16(ah, cbh[kb], acc1[mt], 0, 0, 0);
                acc1[mt] = __builtin_amdgcn_mfma_f32_16x16x32_bf16(al, cbh[kb], acc1[mt], 0, 0, 0);
                acc1[mt] = __builtin_amdgcn_mfma_f32_16x16x32_bf16(ah, cbl[kb], acc1[mt], 0, 0, 0);
            }
        }
        float cbias = cb[d];
        unsigned short* tH = (unsigned short*)t2H;
        unsigned short* tL = (unsigned short*)t2L;
        #pragma unroll
        for (int mt = 0; mt < 6; ++mt) {
            #pragma unroll
            for (int r = 0; r < 4; ++r) {
                int row = mt * 16 + (l >> 4) * 4 + r;
                float v = fmaxf(acc1[mt][r] + cbias, 0.f);
                if (t0 + row >= T1LEN) v = 0.f;
                unsigned short hi = f2bf(v);
                int sw = swz(row, d);
                tH[sw] = hi;
                tL[sw] = f2bf(v - bf2f(hi));
            }
        }
        if (tid < 128) {                   // zero halo rows 96,97
            int row = 96 + (tid >> 6), c = tid & 63;
            int sw = swz(row, c);
            tH[sw] = 0; tL[sw] = 0;
        }
    }
    __syncthreads();

    // ---- conv2 MFMA (verified pattern, 6 M-tiles x 6 kb x 9) ----
    float s_sum = 0.f, s_sq = 0.f;
    {
        int co = w * 16 + (l & 15);
        f32x4 acc[6][3];
        #pragma unroll
        for (int mt = 0; mt < 6; ++mt)
            #pragma unroll
            for (int ct = 0; ct < 3; ++ct)
                acc[mt][ct] = (f32x4){0.f, 0.f, 0.f, 0.f};
        #pragma unroll
        for (int kb = 0; kb < 6; ++kb) {
            #pragma unroll
            for (int mt = 0; mt < 6; ++mt) {
                int row = mt * 16 + (l & 15) + (kb >> 1);
                int cb2 = (kb & 1) * 4 + (l >> 4);
                int si = row * 8 + (cb2 ^ (row & 7));
                short8 ah = __builtin_bit_cast(short8, t2H[si]);
                short8 al = __builtin_bit_cast(short8, t2L[si]);
                acc[mt][0] = __builtin_amdgcn_mfma_f32_16x16x32_bf16(ah, bh[0][kb], acc[mt][0], 0, 0, 0);
                acc[mt][1] = __builtin_amdgcn_mfma_f32_16x16x32_bf16(ah, bh[1][kb], acc[mt][1], 0, 0, 0);
                acc[mt][2] = __builtin_amdgcn_mfma_f32_16x16x32_bf16(ah, bh[2][kb], acc[mt][2], 0, 0, 0);
                acc[mt][0] = __builtin_amdgcn_mfma_f32_16x16x32_bf16(al, bh[0][kb], acc[mt][0], 0, 0, 0);
                acc[mt][1] = __builtin_amdgcn_mfma_f32_16x16x32_bf16(al, bh[1][kb], acc[mt][1], 0, 0, 0);
                acc[mt][2] = __builtin_amdgcn_mfma_f32_16x16x32_bf16(al, bh[2][kb], acc[mt][2], 0, 0, 0);
                acc[mt][0] = __builtin_amdgcn_mfma_f32_16x16x32_bf16(ah, bl[0][kb], acc[mt][0], 0, 0, 0);
                acc[mt][1] = __builtin_amdgcn_mfma_f32_16x16x32_bf16(ah, bl[1][kb], acc[mt][1], 0, 0, 0);
                acc[mt][2] = __builtin_amdgcn_mfma_f32_16x16x32_bf16(ah, bl[2][kb], acc[mt][2], 0, 0, 0);
            }
        }
        float ba = b2a[co], bb = b2b[co], bc = b2c[co];
        #pragma unroll
        for (int mt = 0; mt < 6; ++mt) {
            #pragma unroll
            for (int r = 0; r < 4; ++r) {
                int tl2 = mt * 16 + (l >> 4) * 4 + r;   // local t
                int t = t0 + tl2;
                if (tl2 < TC2 && t < T2LEN) {
                    float P = acc[mt][0][r] + ba, Q = acc[mt][1][r] + bb, Cc = acc[mt][2][r] + bc;
                    float qs = 1.f / (1.f + expf(-Q));
                    float hv = fmaxf(fmaf(P, qs, Cc), 0.f);
                    T2[(t * NN + node) * 64 + co] = hv;
                    s_sum += hv;
                    s_sq = fmaf(hv, hv, s_sq);
                }
            }
        }
    }
    red1[tid] = s_sum; red2[tid] = s_sq;
    __syncthreads();
    for (int off = 128; off > 0; off >>= 1) {
        if (tid < off) { red1[tid] += red1[tid + off]; red2[tid] += red2[tid + off]; }
        __syncthreads();
    }
    if (tid == 0) {
        parts[b * 2]     = red1[0];
        parts[b * 2 + 1] = red2[0];
    }
}

// =========== K2: stats finalize + BN + relu + dot + two-level election final ===========
__global__ __launch_bounds__(256) void k_dotfin(const float* __restrict__ T2,
        const float* __restrict__ parts,
        const float* __restrict__ gamma, const float* __restrict__ beta,
        const float* __restrict__ fcw, const float* __restrict__ fcb,
        float* dpart, float* gdot, int* cnts, float* __restrict__ out) {
    __shared__ float sm[NN * 4];
    __shared__ float r[256];
    __shared__ int lastGrp, lastAll;
    int tid = threadIdx.x;
    if (tid < NN) {
        int n = tid;
        float s = 0.f, q = 0.f;
        for (int i = 0; i < NCHUNK2; ++i) {           // fixed order, deterministic
            s += parts[(n * NCHUNK2 + i) * 2];
            q += parts[(n * NCHUNK2 + i) * 2 + 1];
        }
        float cnt = (float)(T2LEN * 64);
        float mean = s / cnt;
        float var = q / cnt - mean * mean;
        sm[n * 4]     = mean;
        sm[n * 4 + 1] = rsqrtf(var + 1e-5f);
        sm[n * 4 + 2] = gamma[n];
        sm[n * 4 + 3] = beta[n];
    }
    __syncthreads();
    float acc = 0.f;
    const int total4 = T2LEN * NN * 64 / 4;
    const float4* T24 = (const float4*)T2;
    const float4* fw4 = (const float4*)fcw;
    for (int i = blockIdx.x * 256 + tid; i < total4; i += DOT_BLOCKS * 256) {
        float4 t = T24[i];
        float4 f = fw4[i];
        int n = (i >> 4) % NN;
        float mu = sm[n * 4], is = sm[n * 4 + 1], g = sm[n * 4 + 2], bt = sm[n * 4 + 3];
        float v0 = fmaxf((t.x - mu) * is * g + bt, 0.f);
        float v1 = fmaxf((t.y - mu) * is * g + bt, 0.f);
        float v2 = fmaxf((t.z - mu) * is * g + bt, 0.f);
        float v3 = fmaxf((t.w - mu) * is * g + bt, 0.f);
        acc = fmaf(v0, f.x, acc);
        acc = fmaf(v1, f.y, acc);
        acc = fmaf(v2, f.z, acc);
        acc = fmaf(v3, f.w, acc);
    }
    r[tid] = acc;
    __syncthreads();
    for (int off = 128; off > 0; off >>= 1) {
        if (tid < off) r[tid] += r[tid + off];
        __syncthreads();
    }
    int b = blockIdx.x;
    int grp = b >> 4;                       // 16 blocks per group
    if (tid == 0) {
        __hip_atomic_store(&dpart[b], r[0], __ATOMIC_RELEASE, __HIP_MEMORY_SCOPE_AGENT);
        int o = __hip_atomic_fetch_add(&cnts[grp * 32], 1, __ATOMIC_ACQ_REL, __HIP_MEMORY_SCOPE_AGENT);
        lastGrp = (o == 15);
    }
    __syncthreads();
    if (!lastGrp) return;
    // group-elected block: sum its 16 dparts (fixed order)
    if (tid == 0) {
        float s = 0.f;
        #pragma unroll
        for (int i = 0; i < 16; ++i)
            s += __hip_atomic_load(&dpart[grp * 16 + i], __ATOMIC_ACQUIRE, __HIP_MEMORY_SCOPE_AGENT);
        __hip_atomic_store(&gdot[grp], s, __ATOMIC_RELEASE, __HIP_MEMORY_SCOPE_AGENT);
        int o2 = __hip_atomic_fetch_add(&cnts[NGRP * 32], 1, __ATOMIC_ACQ_REL, __HIP_MEMORY_SCOPE_AGENT);
        lastAll = (o2 == NGRP - 1);
    }
    __syncthreads();
    if (!lastAll) return;
    if (tid == 0) {
        float s = 0.f;
        #pragma unroll
        for (int g = 0; g < NGRP; ++g)
            s += __hip_atomic_load(&gdot[g], __ATOMIC_ACQUIRE, __HIP_MEMORY_SCOPE_AGENT);
        out[0] = s + fcb[0];
    }
}

extern "C" void kernel_launch(void* const* d_in, const int* in_sizes, int n_in,
                              void* d_out, int out_size, void* d_ws, size_t ws_size,
                              hipStream_t stream) {
    const float* x     = (const float*)d_in[0];
    // d_in[1] edge_index, d_in[2] edge_weight: unused (ChebConv K=1 -> identity only)
    const float* w1a   = (const float*)d_in[3];
    const float* b1a   = (const float*)d_in[4];
    const float* w1b   = (const float*)d_in[5];
    const float* b1b   = (const float*)d_in[6];
    const float* w1c   = (const float*)d_in[7];
    const float* b1c   = (const float*)d_in[8];
    const float* chw   = (const float*)d_in[9];
    const float* chb   = (const float*)d_in[10];
    const float* w2a   = (const float*)d_in[11];
    const float* b2a   = (const float*)d_in[12];
    const float* w2b   = (const float*)d_in[13];
    const float* b2b   = (const float*)d_in[14];
    const float* w2c   = (const float*)d_in[15];
    const float* b2c   = (const float*)d_in[16];
    const float* gamma = (const float*)d_in[17];
    const float* beta  = (const float*)d_in[18];
    const float* fcw   = (const float*)d_in[19];
    const float* fcb   = (const float*)d_in[20];
    float* out = (float*)d_out;

    char* base = (char*)d_ws;
    float* T2v   = (float*)(base);                 // 1469952 f = 5879808 B
    float* parts = (float*)(base + 5879808);       // 504 f (pad to 2048 B)
    float* dpart = (float*)(base + 5881856);       // 512 f = 2048 B
    float* gdot  = (float*)(base + 5883904);       // 32 f (pad 128 B)
    int*   cnts  = (int*)(base + 5884032);         // 33 x 128 B

    k_fuse<<<NBLK, 256, 0, stream>>>(
        x, w1a, b1a, w1b, b1b, w1c, b1c, chw, chb,
        w2a, w2b, w2c, b2a, b2b, b2c, T2v, parts, cnts);
    k_dotfin<<<DOT_BLOCKS, 256, 0, stream>>>(
        T2v, parts, gamma, beta, fcw, fcb, dpart, gdot, cnts, out);
}

// Round 11
// 30.755 us; speedup vs baseline: 1.7869x; 1.7869x over previous
//
#include <hip/hip_runtime.h>
#include <math.h>

#define NN 18
#define T_STEPS 1280
#define T1LEN 1278   // T-2 (after conv1)
#define T2LEN 1276   // T-4 (after conv2)
#define PREPBLK 144  // 36864 / 256
#define TC2 92
#define NCHUNK2 ((T2LEN + TC2 - 1) / TC2)  // 14
#define NBLK (NCHUNK2 * NN)                // 252 (<=256 CUs -> 1 block/CU)
#define DOT_BLOCKS 512

typedef __attribute__((ext_vector_type(8))) short short8;
typedef __attribute__((ext_vector_type(4))) float f32x4;

__device__ __forceinline__ unsigned short f2bf(float v) {
    unsigned u = __builtin_bit_cast(unsigned, v);
    u = u + 0x7fff + ((u >> 16) & 1);          // RNE
    return (unsigned short)(u >> 16);
}
__device__ __forceinline__ float bf2f(unsigned short h) {
    unsigned u = ((unsigned)h) << 16;
    return __builtin_bit_cast(float, u);
}
// swizzled ushort index for [row][c] bf16 tiles read as uint4 A-fragments (verified R3-R8)
__device__ __forceinline__ int swz(int row, int c) {
    return row * 64 + (((c >> 3) ^ (row & 7)) << 3) + (c & 7);
}

// =========== K0: conv2 weight hi/lo split, layout [kb][col][klocal] (verified R3) ===========
__global__ void k_wprep(const float* __restrict__ wa, const float* __restrict__ wb,
                        const float* __restrict__ wc,
                        unsigned short* __restrict__ WBhi, unsigned short* __restrict__ WBlo) {
    int i = blockIdx.x * 256 + threadIdx.x;
    if (i >= 6 * 192 * 32) return;
    int klocal = i & 31;
    int col = (i >> 5) % 192;
    int kb = i / (192 * 32);
    int conv = col >> 6, co = col & 63;
    int k = kb >> 1, ci = (kb & 1) * 32 + klocal;
    const float* w = (conv == 0) ? wa : (conv == 1 ? wb : wc);
    float v = w[co * 192 + ci * 3 + k];
    unsigned short hi = f2bf(v);
    WBhi[i] = hi;
    WBlo[i] = f2bf(v - bf2f(hi));
}

// =========== K1: per (node, t-chunk 92): x -> conv1(GLU) -> cheb(MFMA) -> conv2(MFMA)
//               -> GLU -> T2 fp32 + BN partials. T1 never hits global memory. ===========
__global__ __launch_bounds__(256) void k_fuseall(const float* __restrict__ x,
        const float* __restrict__ w1a, const float* __restrict__ b1a,
        const float* __restrict__ w1b, const float* __restrict__ b1b,
        const float* __restrict__ w1c, const float* __restrict__ b1c,
        const float* __restrict__ cw, const float* __restrict__ cb,
        const unsigned short* __restrict__ WBhi, const unsigned short* __restrict__ WBlo,
        const float* __restrict__ b2a, const float* __restrict__ b2b,
        const float* __restrict__ b2c,
        float* __restrict__ T2, float* __restrict__ parts) {
    __shared__ float xs[104];
    __shared__ uint4 t1H[768], t1L[768];   // 96 rows x 64 bf16 (swizzled)
    __shared__ uint4 t2H[784], t2L[784];   // 98 rows (96,97 zero)
    __shared__ float red1[256], red2[256];
    int b = blockIdx.x;
    int node = b / NCHUNK2, chunk = b % NCHUNK2;
    int t0 = chunk * TC2;                  // T2 time base; T1 rows t0..t0+95
    int tid = threadIdx.x;
    int l = tid & 63, w = tid >> 6;

    // ---- stage + normalize 98 x values for this node ----
    if (tid < 98) {
        int xt = t0 + tid;
        float v = (xt < T_STEPS) ? x[xt * NN + node] : 0.f;
        xs[tid] = v / fmaxf(fabsf(v), 1e-12f);
    }
    __syncthreads();

    // ---- conv1 + GLU + relu -> t1 tile rows 0..95 (bf16 hi/lo, swizzled) ----
    {
        unsigned short* tH = (unsigned short*)t1H;
        unsigned short* tL = (unsigned short*)t1L;
        int c = l;
        float wa0 = w1a[c*3], wa1 = w1a[c*3+1], wa2 = w1a[c*3+2];
        float wb0 = w1b[c*3], wb1 = w1b[c*3+1], wb2 = w1b[c*3+2];
        float wc0 = w1c[c*3], wc1 = w1c[c*3+1], wc2 = w1c[c*3+2];
        float ba = b1a[c], bb = b1b[c], bc = b1c[c];
        #pragma unroll
        for (int j = 0; j < 24; ++j) {
            int r = w * 24 + j;            // local T1 row, time t0 + r
            float x0 = xs[r], x1 = xs[r + 1], x2 = xs[r + 2];
            float pa = fmaf(wa2, x2, fmaf(wa1, x1, fmaf(wa0, x0, ba)));
            float pb = fmaf(wb2, x2, fmaf(wb1, x1, fmaf(wb0, x0, bb)));
            float pc_ = fmaf(wc2, x2, fmaf(wc1, x1, fmaf(wc0, x0, bc)));
            float q = 1.0f / (1.0f + expf(-pb));
            float v = fmaxf(pa * q + pc_, 0.f);
            if (t0 + r >= T1LEN) v = 0.f;
            unsigned short hi = f2bf(v);
            int sw = swz(r, c);
            tH[sw] = hi;
            tL[sw] = f2bf(v - bf2f(hi));
        }
    }
    // ---- cheb B fragments from cw (hi/lo), wave w -> cols w*16..w*16+15 (verified) ----
    int d = w * 16 + (l & 15);
    short8 cbh[2], cbl[2];
    #pragma unroll
    for (int kb = 0; kb < 2; ++kb) {
        #pragma unroll
        for (int j = 0; j < 8; ++j) {
            float v = cw[(kb * 32 + (l >> 4) * 8 + j) * 64 + d];
            unsigned short hi = f2bf(v);
            cbh[kb][j] = (short)hi;
            cbl[kb][j] = (short)f2bf(v - bf2f(hi));
        }
    }
    __syncthreads();
    // ---- cheb MFMA: 6 M-tiles split-bf16 -> t2 tile rows 0..95; zero 96..97 ----
    {
        f32x4 acc1[6];
        #pragma unroll
        for (int mt = 0; mt < 6; ++mt) acc1[mt] = (f32x4){0.f,0.f,0.f,0.f};
        #pragma unroll
        for (int kb = 0; kb < 2; ++kb) {
            #pragma unroll
            for (int mt = 0; mt < 6; ++mt) {
                int row = mt * 16 + (l & 15);
                int cbi = kb * 4 + (l >> 4);
                int si = row * 8 + (cbi ^ (row & 7));
                short8 ah = __builtin_bit_cast(short8, t1H[si]);
                short8 al = __builtin_bit_cast(short8, t1L[si]);
                acc1[mt] = __builtin_amdgcn_mfma_f32_16x16x32_bf16(ah, cbh[kb], acc1[mt], 0, 0, 0);
                acc1[mt] = __builtin_amdgcn_mfma_f32_16x16x32_bf16(al, cbh[kb], acc1[mt], 0, 0, 0);
                acc1[mt] = __builtin_amdgcn_mfma_f32_16x16x32_bf16(ah, cbl[kb], acc1[mt], 0, 0, 0);
            }
        }
        float cbias = cb[d];
        unsigned short* tH = (unsigned short*)t2H;
        unsigned short* tL = (unsigned short*)t2L;
        #pragma unroll
        for (int mt = 0; mt < 6; ++mt) {
            #pragma unroll
            for (int r = 0; r < 4; ++r) {
                int row = mt * 16 + (l >> 4) * 4 + r;
                float v = fmaxf(acc1[mt][r] + cbias, 0.f);
                if (t0 + row >= T1LEN) v = 0.f;
                unsigned short hi = f2bf(v);
                int sw = swz(row, d);
                tH[sw] = hi;
                tL[sw] = f2bf(v - bf2f(hi));
            }
        }
        // zero halo rows 96,97 (feed only discarded conv2 lanes)
        if (tid < 128) {
            int row = 96 + (tid >> 6), c = tid & 63;
            int sw = swz(row, c);
            tH[sw] = 0; tL[sw] = 0;
        }
    }
    __syncthreads();
    // ---- conv2 MFMA (verified pattern): per-kb coalesced B loads, 6 M-tiles ----
    float s_sum = 0.f, s_sq = 0.f;
    {
        const uint4* wbh = (const uint4*)WBhi;
        const uint4* wbl = (const uint4*)WBlo;
        int co = w * 16 + (l & 15);
        f32x4 acc[6][3];
        #pragma unroll
        for (int mt = 0; mt < 6; ++mt)
            #pragma unroll
            for (int ct = 0; ct < 3; ++ct)
                acc[mt][ct] = (f32x4){0.f, 0.f, 0.f, 0.f};
        for (int kb = 0; kb < 6; ++kb) {
            short8 bh[3], bl[3];
            #pragma unroll
            for (int ct = 0; ct < 3; ++ct) {
                int col = (w + 4 * ct) * 16 + (l & 15);
                int gi = (kb * 192 + col) * 4 + (l >> 4);
                bh[ct] = __builtin_bit_cast(short8, wbh[gi]);
                bl[ct] = __builtin_bit_cast(short8, wbl[gi]);
            }
            #pragma unroll
            for (int mt = 0; mt < 6; ++mt) {
                int row = mt * 16 + (l & 15) + (kb >> 1);
                int cb2 = (kb & 1) * 4 + (l >> 4);
                int si = row * 8 + (cb2 ^ (row & 7));
                short8 ah = __builtin_bit_cast(short8, t2H[si]);
                short8 al = __builtin_bit_cast(short8, t2L[si]);
                acc[mt][0] = __builtin_amdgcn_mfma_f32_16x16x32_bf16(ah, bh[0], acc[mt][0], 0, 0, 0);
                acc[mt][1] = __builtin_amdgcn_mfma_f32_16x16x32_bf16(ah, bh[1], acc[mt][1], 0, 0, 0);
                acc[mt][2] = __builtin_amdgcn_mfma_f32_16x16x32_bf16(ah, bh[2], acc[mt][2], 0, 0, 0);
                acc[mt][0] = __builtin_amdgcn_mfma_f32_16x16x32_bf16(al, bh[0], acc[mt][0], 0, 0, 0);
                acc[mt][1] = __builtin_amdgcn_mfma_f32_16x16x32_bf16(al, bh[1], acc[mt][1], 0, 0, 0);
                acc[mt][2] = __builtin_amdgcn_mfma_f32_16x16x32_bf16(al, bh[2], acc[mt][2], 0, 0, 0);
                acc[mt][0] = __builtin_amdgcn_mfma_f32_16x16x32_bf16(ah, bl[0], acc[mt][0], 0, 0, 0);
                acc[mt][1] = __builtin_amdgcn_mfma_f32_16x16x32_bf16(ah, bl[1], acc[mt][1], 0, 0, 0);
                acc[mt][2] = __builtin_amdgcn_mfma_f32_16x16x32_bf16(ah, bl[2], acc[mt][2], 0, 0, 0);
            }
        }
        float ba = b2a[co], bb = b2b[co], bc = b2c[co];
        #pragma unroll
        for (int mt = 0; mt < 6; ++mt) {
            #pragma unroll
            for (int r = 0; r < 4; ++r) {
                int tl2 = mt * 16 + (l >> 4) * 4 + r;   // local t
                int t = t0 + tl2;
                if (tl2 < TC2 && t < T2LEN) {
                    float P = acc[mt][0][r] + ba, Q = acc[mt][1][r] + bb, Cc = acc[mt][2][r] + bc;
                    float qs = 1.f / (1.f + expf(-Q));
                    float hv = fmaxf(fmaf(P, qs, Cc), 0.f);
                    T2[(t * NN + node) * 64 + co] = hv;
                    s_sum += hv;
                    s_sq = fmaf(hv, hv, s_sq);
                }
            }
        }
    }
    red1[tid] = s_sum; red2[tid] = s_sq;
    __syncthreads();
    for (int off = 128; off > 0; off >>= 1) {
        if (tid < off) { red1[tid] += red1[tid + off]; red2[tid] += red2[tid + off]; }
        __syncthreads();
    }
    if (tid == 0) {
        parts[b * 2]     = red1[0];
        parts[b * 2 + 1] = red2[0];
    }
}

// =========== K2: redundant fixed-order stats finalize + BN + relu + dot (float4) ===========
__global__ __launch_bounds__(256) void k_dot2(const float* __restrict__ T2,
        const float* __restrict__ parts,
        const float* __restrict__ gamma, const float* __restrict__ beta,
        const float* __restrict__ fcw, float* __restrict__ dpart) {
    __shared__ float sm[NN * 4];   // mean, istd, gamma, beta per node
    if (threadIdx.x < NN) {
        int n = threadIdx.x;
        float s = 0.f, q = 0.f;
        for (int i = 0; i < NCHUNK2; ++i) {           // fixed order, deterministic
            s += parts[(n * NCHUNK2 + i) * 2];
            q += parts[(n * NCHUNK2 + i) * 2 + 1];
        }
        float cnt = (float)(T2LEN * 64);
        float mean = s / cnt;
        float var = q / cnt - mean * mean;
        sm[n * 4]     = mean;
        sm[n * 4 + 1] = rsqrtf(var + 1e-5f);
        sm[n * 4 + 2] = gamma[n];
        sm[n * 4 + 3] = beta[n];
    }
    __syncthreads();
    float acc = 0.f;
    const int total4 = T2LEN * NN * 64 / 4;
    const float4* T24 = (const float4*)T2;
    const float4* fw4 = (const float4*)fcw;
    for (int i = blockIdx.x * 256 + threadIdx.x; i < total4; i += DOT_BLOCKS * 256) {
        float4 t = T24[i];
        float4 f = fw4[i];
        int n = (i >> 4) % NN;
        float mu = sm[n * 4], is = sm[n * 4 + 1], g = sm[n * 4 + 2], bt = sm[n * 4 + 3];
        float v0 = fmaxf((t.x - mu) * is * g + bt, 0.f);
        float v1 = fmaxf((t.y - mu) * is * g + bt, 0.f);
        float v2 = fmaxf((t.z - mu) * is * g + bt, 0.f);
        float v3 = fmaxf((t.w - mu) * is * g + bt, 0.f);
        acc = fmaf(v0, f.x, acc);
        acc = fmaf(v1, f.y, acc);
        acc = fmaf(v2, f.z, acc);
        acc = fmaf(v3, f.w, acc);
    }
    __shared__ float r[256];
    r[threadIdx.x] = acc;
    __syncthreads();
    for (int off = 128; off > 0; off >>= 1) {
        if (threadIdx.x < off) r[threadIdx.x] += r[threadIdx.x + off];
        __syncthreads();
    }
    if (threadIdx.x == 0) dpart[blockIdx.x] = r[0];
}

// =========== K3: final reduce + fc_b ===========
__global__ __launch_bounds__(512) void k_final(const float* __restrict__ dpart,
                                               const float* __restrict__ fcb,
                                               float* __restrict__ out) {
    __shared__ float r[512];
    r[threadIdx.x] = dpart[threadIdx.x];
    __syncthreads();
    for (int off = 256; off > 0; off >>= 1) {
        if (threadIdx.x < off) r[threadIdx.x] += r[threadIdx.x + off];
        __syncthreads();
    }
    if (threadIdx.x == 0) out[0] = r[0] + fcb[0];
}

extern "C" void kernel_launch(void* const* d_in, const int* in_sizes, int n_in,
                              void* d_out, int out_size, void* d_ws, size_t ws_size,
                              hipStream_t stream) {
    const float* x     = (const float*)d_in[0];
    // d_in[1] edge_index, d_in[2] edge_weight: unused (ChebConv K=1 -> identity only)
    const float* w1a   = (const float*)d_in[3];
    const float* b1a   = (const float*)d_in[4];
    const float* w1b   = (const float*)d_in[5];
    const float* b1b   = (const float*)d_in[6];
    const float* w1c   = (const float*)d_in[7];
    const float* b1c   = (const float*)d_in[8];
    const float* chw   = (const float*)d_in[9];
    const float* chb   = (const float*)d_in[10];
    const float* w2a   = (const float*)d_in[11];
    const float* b2a   = (const float*)d_in[12];
    const float* w2b   = (const float*)d_in[13];
    const float* b2b   = (const float*)d_in[14];
    const float* w2c   = (const float*)d_in[15];
    const float* b2c   = (const float*)d_in[16];
    const float* gamma = (const float*)d_in[17];
    const float* beta  = (const float*)d_in[18];
    const float* fcw   = (const float*)d_in[19];
    const float* fcb   = (const float*)d_in[20];
    float* out = (float*)d_out;

    char* base = (char*)d_ws;
    float*          T2v   = (float*)(base);                    // 1469952 f = 5879808 B
    unsigned short* WBhi  = (unsigned short*)(base + 5879808); // 73728 B
    unsigned short* WBlo  = (unsigned short*)(base + 5953536); // 73728 B
    float*          parts = (float*)(base + 6027264);          // 504 f
    float*          dpart = (float*)(base + 6030336);          // 512 f

    k_wprep<<<PREPBLK, 256, 0, stream>>>(w2a, w2b, w2c, WBhi, WBlo);
    k_fuseall<<<NBLK, 256, 0, stream>>>(
        x, w1a, b1a, w1b, b1b, w1c, b1c, chw, chb,
        WBhi, WBlo, b2a, b2b, b2c, T2v, parts);
    k_dot2<<<DOT_BLOCKS, 256, 0, stream>>>(T2v, parts, gamma, beta, fcw, dpart);
    k_final<<<1, 512, 0, stream>>>(dpart, fcb, out);
}